// Round 3
// baseline (2151.271 us; speedup 1.0000x reference)
//
#include <hip/hip_runtime.h>
#include <math.h>

// ---------------- problem constants ----------------
#define NIN   64     // 2*B_IN
#define NOUT  32     // 2*B_OUT
#define NL    16     // B_OUT
#define NFIN  16     // F_IN
#define NFOUT 32     // F_OUT
#define NB    8      // BATCH
#define NGRID 24
#define NFREQ 31     // freqs -15..15
#define TOTL  5456   // sum_{l<16} (2l+1)^2
#define NTAB  540144 // 99*TOTL

// workspace float offsets
#define WF_F   0
#define WI_F   349184
#define DGC_F  523776
#define W64_F  785664
#define W32_F  789632
#define XFS_F  791616
#define FX_F   16536640
#define FYC_F  17933376
#define FZ_F   23520320
// total floats: 26,313,792  (~105.3 MB)

#define FZ_FLOATS 2793472  // 256*TOTL float2 = floats
#define NJOBS 1680

__device__ __forceinline__ int offl(int l) { return l * (2 * l - 1) * (2 * l + 1) / 3; }

__device__ __forceinline__ double ipow(double x, int n) {
    double r = 1.0, p = x;
    while (n) { if (n & 1) r *= p; p *= p; n >>= 1; }
    return r;
}

// job table for k_fz: jobs ordered l=15 down to 0; per l: ceil(n1/8)*ceil(n1/2)*4 chunks
__device__ const int JOB_START[17] = {0, 256, 496, 720, 928, 1072, 1204, 1324, 1432,
                                      1496, 1552, 1600, 1640, 1656, 1668, 1676, 1680};

// ---------------- K0: build Wigner + twiddle tables ----------------
__global__ __launch_bounds__(256) void k_tables(float* __restrict__ WF, float* __restrict__ WI,
                                                float2* __restrict__ DGC, float2* __restrict__ W64,
                                                float2* __restrict__ W32) {
    __shared__ double lfs[32];   // log(n!)
    __shared__ double wdh[64];   // DH quadrature weights
    const double PI = 3.14159265358979323846264338327950288;
    int tid = threadIdx.x;
    if (tid < 32) {
        double f = 1.0;
        for (int i = 2; i <= tid; ++i) f *= (double)i;
        lfs[tid] = log(f);
    } else if (tid < 96) {
        int j = tid - 32;
        double x1 = PI * (double)(2 * j + 1) / 128.0;
        double ssum = 0.0;
        for (int k = 0; k < 32; ++k) ssum += sin(x1 * (double)(2 * k + 1)) / (double)(2 * k + 1);
        wdh[j] = (2.0 / 32.0) * sin(x1) * ssum;
    }
    __syncthreads();

    int t = blockIdx.x * 256 + tid;
    if (t >= NTAB) {
        int u = t - NTAB;
        if (u < 31 * 64) {              // forward twiddles e^{-2pi i (f-15) p/64}
            int f = u >> 6, p = u & 63;
            double ang = -2.0 * PI * (double)((f - 15) * p) / 64.0;
            W64[u] = make_float2((float)cos(ang), (float)sin(ang));
        } else {
            u -= 31 * 64;
            if (u < 31 * 32) {          // inverse twiddles e^{+2pi i (mu-15) p/32}
                int mu = u >> 5, p = u & 31;
                double ang = 2.0 * PI * (double)((mu - 15) * p) / 32.0;
                W32[u] = make_float2((float)cos(ang), (float)sin(ang));
            }
        }
        return;
    }
    // decode (l, src, a, b)
    int l = 0;
    while (l < 15 && t >= 99 * offl(l + 1)) l++;
    int n1 = 2 * l + 1, n2 = n1 * n1;
    int r = t - 99 * offl(l);
    int src = r / n2;
    int e = r - src * n2;
    int a = e / n1;
    int b = e - a * n1;
    int mp = a - l, m = b - l;

    double beta;
    if (src < 64)      beta = ((double)src + 0.5) * PI / 64.0;
    else if (src < 96) beta = ((double)(src - 64) + 0.5) * PI / 32.0;
    else               beta = (double)(src - 96 + 1) * PI / 24.0;

    double cb = cos(0.5 * beta), sb = sin(0.5 * beta);
    int smin = (m - mp) > 0 ? (m - mp) : 0;
    int smax = (l + m) < (l - mp) ? (l + m) : (l - mp);
    double pref = 0.5 * (lfs[l + mp] + lfs[l - mp] + lfs[l + m] + lfs[l - m]);
    double logden = lfs[l + m - smin] + lfs[smin] + lfs[mp - m + smin] + lfs[l - mp - smin];
    int p1 = 2 * l + m - mp - 2 * smin;
    int p2 = mp - m + 2 * smin;
    double term = exp(pref - logden) * ipow(cb, p1) * ipow(sb, p2);
    if ((mp - m + smin) & 1) term = -term;
    double acc = term;
    double rr = (sb * sb) / (cb * cb);
    for (int s = smin; s < smax; ++s) {
        term *= -rr * (double)((l + m - s) * (l - mp - s)) / (double)((s + 1) * (mp - m + s + 1));
        acc += term;
    }

    if (src < 64) {
        int j = src;
        WF[64 * offl(l) + (j * n1 + a) * n1 + b] = (float)(acc * wdh[j] / 8192.0);
    } else if (src < 96) {
        int j = src - 64;
        WI[32 * offl(l) + (j * n1 + a) * n1 + b] = (float)((double)(2 * l + 1) * acc);
    } else {
        int bi = src - 96;
        const double SCALING = 0.14433756729740644112728719512549; // 1/sqrt(48)
        double sc = acc * SCALING;
        int base = 24 * offl(l) + a * n1 + b;
        for (int ai = 0; ai < 8; ++ai) {
            double ang = (double)ai * (PI / 4.0) * (double)(a - l);  // conj phase: +i alpha m
            DGC[base + (bi * 8 + ai) * n2] = make_float2((float)(sc * cos(ang)), (float)(sc * sin(ang)));
        }
    }
}

// ---------------- K1: partial forward DFT2 (freqs -15..15) ----------------
__global__ __launch_bounds__(256) void k_dft2(const float* __restrict__ x, const float2* __restrict__ W64,
                                              float2* __restrict__ XFS) {
    __shared__ float  xs[64 * 64];
    __shared__ float2 a1[64 * 16];      // [p][n], n = 0..15
    __shared__ float2 w64s[31 * 65];    // padded rows (65) to kill bank conflicts
    int tid = threadIdx.x;
    int slice = blockIdx.x;
    const float* xp = x + (size_t)slice * 4096;
    for (int i = tid; i < 1024; i += 256) ((float4*)xs)[i] = ((const float4*)xp)[i];
    for (int i = tid; i < 31 * 64; i += 256) { int f = i >> 6, p = i & 63; w64s[f * 65 + p] = W64[i]; }
    __syncthreads();
    // pass 1 over q: A[p][n] = sum_q xs[p][q] * w64[n+15][q]
    for (int o = tid; o < 64 * 16; o += 256) {
        int p = o >> 4, n = o & 15;
        const float* xrow = xs + p * 64;
        const float2* wrow = &w64s[(n + 15) * 65];
        float re = 0.f, im = 0.f;
#pragma unroll 8
        for (int q = 0; q < 64; ++q) { float xv = xrow[q]; float2 w = wrow[q]; re += xv * w.x; im += xv * w.y; }
        a1[p * 16 + n] = make_float2(re, im);
    }
    __syncthreads();
    // pass 2 over p: XF[mu][n] = sum_p a1[p][n]*w64[mu][p];  conj-symmetry fills n<0
    float2* outp = XFS + (size_t)slice * 961;
    for (int o = tid; o < 31 * 16; o += 256) {
        int mu = o >> 4, n = o & 15;
        const float2* wrow = &w64s[mu * 65];
        float re = 0.f, im = 0.f;
#pragma unroll 8
        for (int p = 0; p < 64; ++p) {
            float2 av = a1[p * 16 + n]; float2 w = wrow[p];
            re += av.x * w.x - av.y * w.y;
            im += av.x * w.y + av.y * w.x;
        }
        outp[mu * 31 + (15 + n)] = make_float2(re, im);
        outp[(30 - mu) * 31 + (15 - n)] = make_float2(re, -im);
    }
}

// ---------------- K2: Fy~ = conj(D)*ker, layout [(o,n)][(i,k)] per l ----------------
__global__ __launch_bounds__(256) void k_fy(const float* __restrict__ ker, const float2* __restrict__ DGC,
                                            float2* __restrict__ FYC) {
    int t = blockIdx.x * 256 + threadIdx.x;
    if (t >= 512 * TOTL) return;
    int l = 0;
    while (l < 15 && t >= 512 * offl(l + 1)) l++;
    int n1 = 2 * l + 1, n2 = n1 * n1;
    int r = t - 512 * offl(l);
    int k = r % n1; r /= n1;
    int i = r & 15; r >>= 4;
    int n = r % n1; int o = r / n1;
    const float2* dg = DGC + 24 * offl(l) + n * n1 + k;
    const float* kp = ker + (i * 32 + o) * 24;
    float re = 0.f, im = 0.f;
#pragma unroll
    for (int g = 0; g < 24; ++g) {
        float2 d = dg[g * n2];
        float kv = kp[g];
        re += d.x * kv; im += d.y * kv;
    }
    FYC[t] = make_float2(re, im);
}

// ---------------- K3: Fx = sum_j WF[l][j]*XF, layout [(b,m)][(i,k)] per l ----------------
__global__ __launch_bounds__(256) void k_fx(const float2* __restrict__ XFS, const float* __restrict__ WF,
                                            float2* __restrict__ FX) {
    int t = blockIdx.x * 256 + threadIdx.x;
    if (t >= 128 * TOTL) return;
    int l = 0;
    while (l < 15 && t >= 128 * offl(l + 1)) l++;
    int n1 = 2 * l + 1, n2 = n1 * n1;
    int r = t - 128 * offl(l);
    int k = r % n1; r /= n1;
    int i = r & 15; r >>= 4;
    int m = r % n1; int b = r / n1;
    const float* wf = WF + 64 * offl(l) + m * n1 + k;
    const float2* xf = XFS + (size_t)((b * 16 + i) * 64) * 961 + (m - l + 15) * 31 + (k - l + 15);
    float re = 0.f, im = 0.f;
#pragma unroll 8
    for (int j = 0; j < 64; ++j) {
        float w = wf[j * n2];
        float2 v = xf[j * 961];
        re += w * v.x; im += w * v.y;
    }
    FX[t] = make_float2(re, im);
}

// ---------------- K3b: zero FZ + job counter ----------------
__global__ __launch_bounds__(256) void k_zero(float4* __restrict__ FZ4, int* __restrict__ cnt) {
    int t = blockIdx.x * 256 + threadIdx.x;
    FZ4[t] = make_float4(0.f, 0.f, 0.f, 0.f);   // grid sized exactly FZ_FLOATS/4
    if (t == 0) *cnt = 0;
}

// ---------------- K4: Fz complex GEMM, persistent blocks + dynamic jobs ----------------
// job = (l desc, tm, tn, ic); atomically accumulates C[(b,m)][(o,n)] over i-chunk ic
__global__ __launch_bounds__(256, 4) void k_fz(const float2* __restrict__ FX, const float2* __restrict__ FYC,
                                               float2* __restrict__ FZ, int* __restrict__ cnt) {
    __shared__ float2 As[64][17];
    __shared__ float2 Bs[64][17];
    __shared__ int sjob;
    int tid = threadIdx.x;
    int kk0 = tid & 15;
    int rr0 = tid >> 4;
    int ty = tid >> 4;
    int tx = tid & 15;

    for (;;) {
        if (tid == 0) sjob = atomicAdd(cnt, 1);
        __syncthreads();
        int bid = sjob;
        if (bid >= NJOBS) return;

        int li = 0;
        while (li < 15 && bid >= JOB_START[li + 1]) ++li;
        int l = 15 - li;
        int n1 = 2 * l + 1;
        int ntn = (n1 + 1) >> 1;
        int r = bid - JOB_START[li];
        int ic = r & 3; r >>= 2;
        int tn = r % ntn;
        int tm = r / ntn;
        int M = 8 * n1, N = 32 * n1, K = 16 * n1;
        int kend = 4 * n1;          // chunk length
        int cbase = ic * kend;
        const float2* A = FX + 128 * offl(l);
        const float2* B = FYC + 512 * offl(l);
        float2* C = FZ + 256 * offl(l);

        float acr[4][4] = {{0}}, aci[4][4] = {{0}};
        float2 ar[4], br[4];
        // prologue: load k0=0 slab into regs
        {
            int kc = kk0;
            bool kok = kc < kend;
#pragma unroll
            for (int s = 0; s < 4; ++s) {
                int row = rr0 + 16 * s;
                int grow = tm * 64 + row;
                ar[s] = (kok && grow < M) ? A[(size_t)grow * K + cbase + kc] : make_float2(0.f, 0.f);
                int gcol = tn * 64 + row;
                br[s] = (kok && gcol < N) ? B[(size_t)gcol * K + cbase + kc] : make_float2(0.f, 0.f);
            }
        }
        for (int k0 = 0; k0 < kend; k0 += 16) {
            __syncthreads();   // previous compute (or previous job) done with LDS
#pragma unroll
            for (int s = 0; s < 4; ++s) {
                As[rr0 + 16 * s][kk0] = ar[s];
                Bs[rr0 + 16 * s][kk0] = br[s];
            }
            __syncthreads();   // LDS tile ready
            // prefetch next slab into regs (overlaps compute below)
            if (k0 + 16 < kend) {
                int kc = k0 + 16 + kk0;
                bool kok = kc < kend;
#pragma unroll
                for (int s = 0; s < 4; ++s) {
                    int row = rr0 + 16 * s;
                    int grow = tm * 64 + row;
                    ar[s] = (kok && grow < M) ? A[(size_t)grow * K + cbase + kc] : make_float2(0.f, 0.f);
                    int gcol = tn * 64 + row;
                    br[s] = (kok && gcol < N) ? B[(size_t)gcol * K + cbase + kc] : make_float2(0.f, 0.f);
                }
            }
#pragma unroll
            for (int kk = 0; kk < 16; ++kk) {
                float2 av[4], bv[4];
#pragma unroll
                for (int ii = 0; ii < 4; ++ii) av[ii] = As[ty + 16 * ii][kk];
#pragma unroll
                for (int jj = 0; jj < 4; ++jj) bv[jj] = Bs[tx + 16 * jj][kk];
#pragma unroll
                for (int ii = 0; ii < 4; ++ii)
#pragma unroll
                    for (int jj = 0; jj < 4; ++jj) {
                        acr[ii][jj] += av[ii].x * bv[jj].x - av[ii].y * bv[jj].y;
                        aci[ii][jj] += av[ii].x * bv[jj].y + av[ii].y * bv[jj].x;
                    }
            }
        }
#pragma unroll
        for (int ii = 0; ii < 4; ++ii) {
            int row = tm * 64 + ty + 16 * ii;
            if (row >= M) continue;
#pragma unroll
            for (int jj = 0; jj < 4; ++jj) {
                int col = tn * 64 + tx + 16 * jj;
                if (col < N) {
                    float2* cp = &C[(size_t)row * N + col];
                    atomicAdd(&cp->x, acr[ii][jj]);
                    atomicAdd(&cp->y, aci[ii][jj]);
                }
            }
        }
    }
}

// ---------------- K5: fused S-assembly + inverse DFT2 + bias ----------------
__global__ __launch_bounds__(256) void k_out(const float2* __restrict__ FZ, const float* __restrict__ WI,
                                             const float2* __restrict__ W32, const float* __restrict__ bias,
                                             float* __restrict__ out) {
    __shared__ float2 s31[961];
    __shared__ float2 w32s[31 * 33];  // padded
    __shared__ float2 T[31 * 32];     // [mu][q]
    int tid = threadIdx.x;
    int slice = blockIdx.x;
    int j = slice & 31;
    int o = (slice >> 5) & 31;
    int b = slice >> 10;
    for (int i = tid; i < 992; i += 256) { int mu = i >> 5, p = i & 31; w32s[mu * 33 + p] = W32[i]; }
    // phase A: s31[mu,nu] = sum_l WI[l][j,m,n] * Fz[l][b,o,m,n]
    for (int t = tid; t < 961; t += 256) {
        int mu = t / 31;
        int nu = t - mu * 31;
        int m = mu - 15, n = nu - 15;
        int am = m < 0 ? -m : m, an = n < 0 ? -n : n;
        int l0 = am > an ? am : an;
        float re = 0.f, im = 0.f;
        for (int l = l0; l < 16; ++l) {
            int n1 = 2 * l + 1;
            int off = offl(l);
            float w = WI[32 * off + (j * n1 + (m + l)) * n1 + (n + l)];
            float2 z = FZ[256 * off + (size_t)(b * n1 + (m + l)) * (32 * n1) + o * n1 + (n + l)];
            re += w * z.x; im += w * z.y;
        }
        s31[t] = make_float2(re, im);
    }
    __syncthreads();
    // phase B: T[mu][q] = sum_nu s31[mu][nu] * w32[nu][q]
    for (int t = tid; t < 992; t += 256) {
        int mu = t >> 5, q = t & 31;
        const float2* srow = s31 + mu * 31;
        float re = 0.f, im = 0.f;
#pragma unroll
        for (int nu = 0; nu < 31; ++nu) {
            float2 sv = srow[nu]; float2 w = w32s[nu * 33 + q];
            re += sv.x * w.x - sv.y * w.y;
            im += sv.x * w.y + sv.y * w.x;
        }
        T[mu * 32 + q] = make_float2(re, im);
    }
    __syncthreads();
    // phase C: out[p][q] = Re( sum_mu T[mu][q] * w32[mu][p] ) + bias
    float bv = bias[o];
    float* op = out + (size_t)slice * 1024;
    for (int t = tid; t < 1024; t += 256) {
        int p = t >> 5, q = t & 31;
        float acc = 0.f;
#pragma unroll
        for (int mu = 0; mu < 31; ++mu) {
            float2 tv = T[mu * 32 + q]; float2 w = w32s[mu * 33 + p];
            acc += tv.x * w.x - tv.y * w.y;
        }
        op[t] = acc + bv;
    }
}

// ---------------- launch ----------------
extern "C" void kernel_launch(void* const* d_in, const int* in_sizes, int n_in,
                              void* d_out, int out_size, void* d_ws, size_t ws_size,
                              hipStream_t stream) {
    const float* x    = (const float*)d_in[0];
    const float* ker  = (const float*)d_in[1];
    const float* bias = (const float*)d_in[2];
    float* out = (float*)d_out;
    float* wsf = (float*)d_ws;

    float*  WF   = wsf + WF_F;
    float*  WI   = wsf + WI_F;
    float2* DGC  = (float2*)(wsf + DGC_F);
    float2* W64  = (float2*)(wsf + W64_F);
    float2* W32  = (float2*)(wsf + W32_F);
    float2* XFS  = (float2*)(wsf + XFS_F);
    float2* FX   = (float2*)(wsf + FX_F);
    float2* FYC  = (float2*)(wsf + FYC_F);
    float2* FZ   = (float2*)(wsf + FZ_F);
    int*    CNT  = (int*)(wsf + XFS_F);   // XFS region dead after k_fx

    hipLaunchKernelGGL(k_tables, dim3(2122),  dim3(256), 0, stream, WF, WI, DGC, W64, W32);
    hipLaunchKernelGGL(k_dft2,   dim3(8192),  dim3(256), 0, stream, x, W64, XFS);
    hipLaunchKernelGGL(k_fy,     dim3(10912), dim3(256), 0, stream, ker, DGC, FYC);
    hipLaunchKernelGGL(k_fx,     dim3(2728),  dim3(256), 0, stream, XFS, WF, FX);
    hipLaunchKernelGGL(k_zero,   dim3(2728),  dim3(256), 0, stream, (float4*)FZ, CNT);
    hipLaunchKernelGGL(k_fz,     dim3(1024),  dim3(256), 0, stream, FX, FYC, FZ, CNT);
    hipLaunchKernelGGL(k_out,    dim3(8192),  dim3(256), 0, stream, FZ, WI, W32, bias, out);
}

// Round 4
// 860.767 us; speedup vs baseline: 2.4993x; 2.4993x over previous
//
#include <hip/hip_runtime.h>
#include <math.h>

// ---------------- problem constants ----------------
#define NIN   64     // 2*B_IN
#define NOUT  32     // 2*B_OUT
#define NL    16     // B_OUT
#define NFIN  16     // F_IN
#define NFOUT 32     // F_OUT
#define NB    8      // BATCH
#define NGRID 24
#define NFREQ 31     // freqs -15..15
#define TOTL  5456   // sum_{l<16} (2l+1)^2
#define NTAB  540144 // 99*TOTL

// workspace float offsets
#define WF_F   0
#define WI_F   349184
#define DGC_F  523776
#define W64_F  785664
#define W32_F  789632
#define XFS_F  791616
#define FX_F   16536640
#define FYC_F  17933376
#define FZ_F   23520320
// total floats: 26,313,792  (~105.3 MB)

#define FZ_ELEMS 1396736   // 256*TOTL float2 elements per FZ buffer
#define NJOBS 1680
#define CNT_OFF (XFS_F + 3 * 2 * FZ_ELEMS)   // int slot after the 3 partial buffers (in XFS region)

__device__ __forceinline__ int offl(int l) { return l * (2 * l - 1) * (2 * l + 1) / 3; }

__device__ __forceinline__ double ipow(double x, int n) {
    double r = 1.0, p = x;
    while (n) { if (n & 1) r *= p; p *= p; n >>= 1; }
    return r;
}

// job table for k_fz: jobs ordered l=15 down to 0; per l: ceil(M/64)*ceil(N/64)*4 chunks
__device__ const int JOB_START[17] = {0, 256, 496, 720, 928, 1072, 1204, 1324, 1432,
                                      1496, 1552, 1600, 1640, 1656, 1668, 1676, 1680};

// ---------------- K0: build Wigner + twiddle tables ----------------
__global__ __launch_bounds__(256) void k_tables(float* __restrict__ WF, float* __restrict__ WI,
                                                float2* __restrict__ DGC, float2* __restrict__ W64,
                                                float2* __restrict__ W32) {
    __shared__ double lfs[32];   // log(n!)
    __shared__ double wdh[64];   // DH quadrature weights
    const double PI = 3.14159265358979323846264338327950288;
    int tid = threadIdx.x;
    if (tid < 32) {
        double f = 1.0;
        for (int i = 2; i <= tid; ++i) f *= (double)i;
        lfs[tid] = log(f);
    } else if (tid < 96) {
        int j = tid - 32;
        double x1 = PI * (double)(2 * j + 1) / 128.0;
        double ssum = 0.0;
        for (int k = 0; k < 32; ++k) ssum += sin(x1 * (double)(2 * k + 1)) / (double)(2 * k + 1);
        wdh[j] = (2.0 / 32.0) * sin(x1) * ssum;
    }
    __syncthreads();

    int t = blockIdx.x * 256 + tid;
    if (t >= NTAB) {
        int u = t - NTAB;
        if (u < 31 * 64) {              // forward twiddles e^{-2pi i (f-15) p/64}
            int f = u >> 6, p = u & 63;
            double ang = -2.0 * PI * (double)((f - 15) * p) / 64.0;
            W64[u] = make_float2((float)cos(ang), (float)sin(ang));
        } else {
            u -= 31 * 64;
            if (u < 31 * 32) {          // inverse twiddles e^{+2pi i (mu-15) p/32}
                int mu = u >> 5, p = u & 31;
                double ang = 2.0 * PI * (double)((mu - 15) * p) / 32.0;
                W32[u] = make_float2((float)cos(ang), (float)sin(ang));
            }
        }
        return;
    }
    // decode (l, src, a, b)
    int l = 0;
    while (l < 15 && t >= 99 * offl(l + 1)) l++;
    int n1 = 2 * l + 1, n2 = n1 * n1;
    int r = t - 99 * offl(l);
    int src = r / n2;
    int e = r - src * n2;
    int a = e / n1;
    int b = e - a * n1;
    int mp = a - l, m = b - l;

    double beta;
    if (src < 64)      beta = ((double)src + 0.5) * PI / 64.0;
    else if (src < 96) beta = ((double)(src - 64) + 0.5) * PI / 32.0;
    else               beta = (double)(src - 96 + 1) * PI / 24.0;

    double cb = cos(0.5 * beta), sb = sin(0.5 * beta);
    int smin = (m - mp) > 0 ? (m - mp) : 0;
    int smax = (l + m) < (l - mp) ? (l + m) : (l - mp);
    double pref = 0.5 * (lfs[l + mp] + lfs[l - mp] + lfs[l + m] + lfs[l - m]);
    double logden = lfs[l + m - smin] + lfs[smin] + lfs[mp - m + smin] + lfs[l - mp - smin];
    int p1 = 2 * l + m - mp - 2 * smin;
    int p2 = mp - m + 2 * smin;
    double term = exp(pref - logden) * ipow(cb, p1) * ipow(sb, p2);
    if ((mp - m + smin) & 1) term = -term;
    double acc = term;
    double rr = (sb * sb) / (cb * cb);
    for (int s = smin; s < smax; ++s) {
        term *= -rr * (double)((l + m - s) * (l - mp - s)) / (double)((s + 1) * (mp - m + s + 1));
        acc += term;
    }

    if (src < 64) {
        int j = src;
        WF[64 * offl(l) + (j * n1 + a) * n1 + b] = (float)(acc * wdh[j] / 8192.0);
    } else if (src < 96) {
        int j = src - 64;
        WI[32 * offl(l) + (j * n1 + a) * n1 + b] = (float)((double)(2 * l + 1) * acc);
    } else {
        int bi = src - 96;
        const double SCALING = 0.14433756729740644112728719512549; // 1/sqrt(48)
        double sc = acc * SCALING;
        int base = 24 * offl(l) + a * n1 + b;
        for (int ai = 0; ai < 8; ++ai) {
            double ang = (double)ai * (PI / 4.0) * (double)(a - l);  // conj phase: +i alpha m
            DGC[base + (bi * 8 + ai) * n2] = make_float2((float)(sc * cos(ang)), (float)(sc * sin(ang)));
        }
    }
}

// ---------------- K1: partial forward DFT2 (freqs -15..15) ----------------
__global__ __launch_bounds__(256) void k_dft2(const float* __restrict__ x, const float2* __restrict__ W64,
                                              float2* __restrict__ XFS) {
    __shared__ float  xs[64 * 64];
    __shared__ float2 a1[64 * 16];      // [p][n], n = 0..15
    __shared__ float2 w64s[31 * 65];    // padded rows (65) to kill bank conflicts
    int tid = threadIdx.x;
    int slice = blockIdx.x;
    const float* xp = x + (size_t)slice * 4096;
    for (int i = tid; i < 1024; i += 256) ((float4*)xs)[i] = ((const float4*)xp)[i];
    for (int i = tid; i < 31 * 64; i += 256) { int f = i >> 6, p = i & 63; w64s[f * 65 + p] = W64[i]; }
    __syncthreads();
    // pass 1 over q: A[p][n] = sum_q xs[p][q] * w64[n+15][q]
    for (int o = tid; o < 64 * 16; o += 256) {
        int p = o >> 4, n = o & 15;
        const float* xrow = xs + p * 64;
        const float2* wrow = &w64s[(n + 15) * 65];
        float re = 0.f, im = 0.f;
#pragma unroll 8
        for (int q = 0; q < 64; ++q) { float xv = xrow[q]; float2 w = wrow[q]; re += xv * w.x; im += xv * w.y; }
        a1[p * 16 + n] = make_float2(re, im);
    }
    __syncthreads();
    // pass 2 over p: XF[mu][n] = sum_p a1[p][n]*w64[mu][p];  conj-symmetry fills n<0
    float2* outp = XFS + (size_t)slice * 961;
    for (int o = tid; o < 31 * 16; o += 256) {
        int mu = o >> 4, n = o & 15;
        const float2* wrow = &w64s[mu * 65];
        float re = 0.f, im = 0.f;
#pragma unroll 8
        for (int p = 0; p < 64; ++p) {
            float2 av = a1[p * 16 + n]; float2 w = wrow[p];
            re += av.x * w.x - av.y * w.y;
            im += av.x * w.y + av.y * w.x;
        }
        outp[mu * 31 + (15 + n)] = make_float2(re, im);
        outp[(30 - mu) * 31 + (15 - n)] = make_float2(re, -im);
    }
}

// ---------------- K2: Fy~ = conj(D)*ker, layout [(o,n)][(i,k)] per l ----------------
__global__ __launch_bounds__(256) void k_fy(const float* __restrict__ ker, const float2* __restrict__ DGC,
                                            float2* __restrict__ FYC) {
    int t = blockIdx.x * 256 + threadIdx.x;
    if (t >= 512 * TOTL) return;
    int l = 0;
    while (l < 15 && t >= 512 * offl(l + 1)) l++;
    int n1 = 2 * l + 1, n2 = n1 * n1;
    int r = t - 512 * offl(l);
    int k = r % n1; r /= n1;
    int i = r & 15; r >>= 4;
    int n = r % n1; int o = r / n1;
    const float2* dg = DGC + 24 * offl(l) + n * n1 + k;
    const float* kp = ker + (i * 32 + o) * 24;
    float re = 0.f, im = 0.f;
#pragma unroll
    for (int g = 0; g < 24; ++g) {
        float2 d = dg[g * n2];
        float kv = kp[g];
        re += d.x * kv; im += d.y * kv;
    }
    FYC[t] = make_float2(re, im);
}

// ---------------- K3: Fx = sum_j WF[l][j]*XF, layout [(b,m)][(i,k)] per l ----------------
__global__ __launch_bounds__(256) void k_fx(const float2* __restrict__ XFS, const float* __restrict__ WF,
                                            float2* __restrict__ FX) {
    int t = blockIdx.x * 256 + threadIdx.x;
    if (t >= 128 * TOTL) return;
    int l = 0;
    while (l < 15 && t >= 128 * offl(l + 1)) l++;
    int n1 = 2 * l + 1, n2 = n1 * n1;
    int r = t - 128 * offl(l);
    int k = r % n1; r /= n1;
    int i = r & 15; r >>= 4;
    int m = r % n1; int b = r / n1;
    const float* wf = WF + 64 * offl(l) + m * n1 + k;
    const float2* xf = XFS + (size_t)((b * 16 + i) * 64) * 961 + (m - l + 15) * 31 + (k - l + 15);
    float re = 0.f, im = 0.f;
#pragma unroll 8
    for (int j = 0; j < 64; ++j) {
        float w = wf[j * n2];
        float2 v = xf[j * 961];
        re += w * v.x; im += w * v.y;
    }
    FX[t] = make_float2(re, im);
}

// ---------------- K4: Fz complex GEMM, persistent blocks + dynamic jobs ----------------
// job = (l desc, tm, tn, ic); writes partial C[(b,m)][(o,n)] for i-chunk ic into P[ic]
__global__ __launch_bounds__(256) void k_fz(const float2* __restrict__ FX, const float2* __restrict__ FYC,
                                            float2* __restrict__ P0, float2* __restrict__ P1,
                                            float2* __restrict__ P2, float2* __restrict__ P3,
                                            int* __restrict__ cnt) {
    __shared__ float2 As[2][64][17];
    __shared__ float2 Bs[2][64][17];
    __shared__ int sjob;
    int tid = threadIdx.x;
    int kk0 = tid & 15;
    int rr0 = tid >> 4;
    int ty = tid >> 4;
    int tx = tid & 15;

    for (;;) {
        if (tid == 0) sjob = atomicAdd(cnt, 1);
        __syncthreads();        // publishes sjob; also fences LDS reuse across jobs
        int bid = sjob;
        if (bid >= NJOBS) return;

        int li = 0;
        while (li < 15 && bid >= JOB_START[li + 1]) ++li;
        int l = 15 - li;
        int n1 = 2 * l + 1;
        int ntn = (n1 + 1) >> 1;
        int r = bid - JOB_START[li];
        int ic = r & 3; r >>= 2;
        int tn = r % ntn;
        int tm = r / ntn;
        int M = 8 * n1, N = 32 * n1, K = 16 * n1;
        int kend = 4 * n1;          // chunk length
        int cbase = ic * kend;
        const float2* A = FX + 128 * offl(l);
        const float2* B = FYC + 512 * offl(l);
        float2* C = (ic == 0 ? P0 : ic == 1 ? P1 : ic == 2 ? P2 : P3) + 256 * offl(l);

        float acr[4][4] = {{0}}, aci[4][4] = {{0}};
        float2 ar[4], br[4];
        // prologue: load slab k0=0 into regs
        {
            int kc = kk0;
            bool kok = kc < kend;
#pragma unroll
            for (int s = 0; s < 4; ++s) {
                int row = rr0 + 16 * s;
                int grow = tm * 64 + row;
                ar[s] = (kok && grow < M) ? A[(size_t)grow * K + cbase + kc] : make_float2(0.f, 0.f);
                int gcol = tn * 64 + row;
                br[s] = (kok && gcol < N) ? B[(size_t)gcol * K + cbase + kc] : make_float2(0.f, 0.f);
            }
        }
        int cur = 0;
        for (int k0 = 0; k0 < kend; k0 += 16) {
#pragma unroll
            for (int s = 0; s < 4; ++s) {
                As[cur][rr0 + 16 * s][kk0] = ar[s];
                Bs[cur][rr0 + 16 * s][kk0] = br[s];
            }
            __syncthreads();   // tile[cur] ready (and everyone done with tile[cur] reads from 2 steps ago)
            // prefetch next slab into regs (overlaps compute below)
            if (k0 + 16 < kend) {
                int kc = k0 + 16 + kk0;
                bool kok = kc < kend;
#pragma unroll
                for (int s = 0; s < 4; ++s) {
                    int row = rr0 + 16 * s;
                    int grow = tm * 64 + row;
                    ar[s] = (kok && grow < M) ? A[(size_t)grow * K + cbase + kc] : make_float2(0.f, 0.f);
                    int gcol = tn * 64 + row;
                    br[s] = (kok && gcol < N) ? B[(size_t)gcol * K + cbase + kc] : make_float2(0.f, 0.f);
                }
            }
#pragma unroll
            for (int kk = 0; kk < 16; ++kk) {
                float2 av[4], bv[4];
#pragma unroll
                for (int ii = 0; ii < 4; ++ii) av[ii] = As[cur][ty + 16 * ii][kk];
#pragma unroll
                for (int jj = 0; jj < 4; ++jj) bv[jj] = Bs[cur][tx + 16 * jj][kk];
#pragma unroll
                for (int ii = 0; ii < 4; ++ii)
#pragma unroll
                    for (int jj = 0; jj < 4; ++jj) {
                        acr[ii][jj] += av[ii].x * bv[jj].x - av[ii].y * bv[jj].y;
                        aci[ii][jj] += av[ii].x * bv[jj].y + av[ii].y * bv[jj].x;
                    }
            }
            cur ^= 1;
        }
#pragma unroll
        for (int ii = 0; ii < 4; ++ii) {
            int row = tm * 64 + ty + 16 * ii;
            if (row >= M) continue;
#pragma unroll
            for (int jj = 0; jj < 4; ++jj) {
                int col = tn * 64 + tx + 16 * jj;
                if (col < N) C[(size_t)row * N + col] = make_float2(acr[ii][jj], aci[ii][jj]);
            }
        }
        __syncthreads();       // all reads of LDS done before next job overwrites
    }
}

// ---------------- K4b: FZ = P0 + P1 + P2 + P3 ----------------
__global__ __launch_bounds__(256) void k_reduce(float4* __restrict__ FZ, const float4* __restrict__ P1,
                                                const float4* __restrict__ P2, const float4* __restrict__ P3) {
    int t = blockIdx.x * 256 + threadIdx.x;
    if (t >= FZ_ELEMS / 2) return;   // float2 pairs as float4
    float4 a = FZ[t], b = P1[t], c = P2[t], d = P3[t];
    a.x += b.x + c.x + d.x;
    a.y += b.y + c.y + d.y;
    a.z += b.z + c.z + d.z;
    a.w += b.w + c.w + d.w;
    FZ[t] = a;
}

// ---------------- K5: fused S-assembly + inverse DFT2 + bias ----------------
__global__ __launch_bounds__(256) void k_out(const float2* __restrict__ FZ, const float* __restrict__ WI,
                                             const float2* __restrict__ W32, const float* __restrict__ bias,
                                             float* __restrict__ out) {
    __shared__ float2 s31[961];
    __shared__ float2 w32s[31 * 33];  // padded
    __shared__ float2 T[31 * 32];     // [mu][q]
    int tid = threadIdx.x;
    int slice = blockIdx.x;
    int j = slice & 31;
    int o = (slice >> 5) & 31;
    int b = slice >> 10;
    for (int i = tid; i < 992; i += 256) { int mu = i >> 5, p = i & 31; w32s[mu * 33 + p] = W32[i]; }
    // phase A: s31[mu,nu] = sum_l WI[l][j,m,n] * Fz[l][b,o,m,n]
    for (int t = tid; t < 961; t += 256) {
        int mu = t / 31;
        int nu = t - mu * 31;
        int m = mu - 15, n = nu - 15;
        int am = m < 0 ? -m : m, an = n < 0 ? -n : n;
        int l0 = am > an ? am : an;
        float re = 0.f, im = 0.f;
        for (int l = l0; l < 16; ++l) {
            int n1 = 2 * l + 1;
            int off = offl(l);
            float w = WI[32 * off + (j * n1 + (m + l)) * n1 + (n + l)];
            float2 z = FZ[256 * off + (size_t)(b * n1 + (m + l)) * (32 * n1) + o * n1 + (n + l)];
            re += w * z.x; im += w * z.y;
        }
        s31[t] = make_float2(re, im);
    }
    __syncthreads();
    // phase B: T[mu][q] = sum_nu s31[mu][nu] * w32[nu][q]
    for (int t = tid; t < 992; t += 256) {
        int mu = t >> 5, q = t & 31;
        const float2* srow = s31 + mu * 31;
        float re = 0.f, im = 0.f;
#pragma unroll
        for (int nu = 0; nu < 31; ++nu) {
            float2 sv = srow[nu]; float2 w = w32s[nu * 33 + q];
            re += sv.x * w.x - sv.y * w.y;
            im += sv.x * w.y + sv.y * w.x;
        }
        T[mu * 32 + q] = make_float2(re, im);
    }
    __syncthreads();
    // phase C: out[p][q] = Re( sum_mu T[mu][q] * w32[mu][p] ) + bias
    float bv = bias[o];
    float* op = out + (size_t)slice * 1024;
    for (int t = tid; t < 1024; t += 256) {
        int p = t >> 5, q = t & 31;
        float acc = 0.f;
#pragma unroll
        for (int mu = 0; mu < 31; ++mu) {
            float2 tv = T[mu * 32 + q]; float2 w = w32s[mu * 33 + p];
            acc += tv.x * w.x - tv.y * w.y;
        }
        op[t] = acc + bv;
    }
}

// ---------------- launch ----------------
extern "C" void kernel_launch(void* const* d_in, const int* in_sizes, int n_in,
                              void* d_out, int out_size, void* d_ws, size_t ws_size,
                              hipStream_t stream) {
    const float* x    = (const float*)d_in[0];
    const float* ker  = (const float*)d_in[1];
    const float* bias = (const float*)d_in[2];
    float* out = (float*)d_out;
    float* wsf = (float*)d_ws;

    float*  WF   = wsf + WF_F;
    float*  WI   = wsf + WI_F;
    float2* DGC  = (float2*)(wsf + DGC_F);
    float2* W64  = (float2*)(wsf + W64_F);
    float2* W32  = (float2*)(wsf + W32_F);
    float2* XFS  = (float2*)(wsf + XFS_F);
    float2* FX   = (float2*)(wsf + FX_F);
    float2* FYC  = (float2*)(wsf + FYC_F);
    float2* FZ   = (float2*)(wsf + FZ_F);
    // split-K partials for chunks 1..3 + job counter live in the (dead-after-k_fx) XFS region
    float2* FZP1 = XFS;
    float2* FZP2 = FZP1 + FZ_ELEMS;
    float2* FZP3 = FZP2 + FZ_ELEMS;
    int*    CNT  = (int*)(wsf + CNT_OFF);

    hipLaunchKernelGGL(k_tables, dim3(2122),  dim3(256), 0, stream, WF, WI, DGC, W64, W32);
    hipLaunchKernelGGL(k_dft2,   dim3(8192),  dim3(256), 0, stream, x, W64, XFS);
    hipLaunchKernelGGL(k_fy,     dim3(10912), dim3(256), 0, stream, ker, DGC, FYC);
    hipLaunchKernelGGL(k_fx,     dim3(2728),  dim3(256), 0, stream, XFS, WF, FX);
    hipMemsetAsync(CNT, 0, sizeof(int), stream);   // reset job queue (XFS data dead now)
    hipLaunchKernelGGL(k_fz,     dim3(1024),  dim3(256), 0, stream, FX, FYC, FZ, FZP1, FZP2, FZP3, CNT);
    hipLaunchKernelGGL(k_reduce, dim3(2728),  dim3(256), 0, stream, (float4*)FZ, (const float4*)FZP1,
                                                                   (const float4*)FZP2, (const float4*)FZP3);
    hipLaunchKernelGGL(k_out,    dim3(8192),  dim3(256), 0, stream, FZ, WI, W32, bias, out);
}

// Round 5
// 807.261 us; speedup vs baseline: 2.6649x; 1.0663x over previous
//
#include <hip/hip_runtime.h>
#include <math.h>

// ---------------- problem constants ----------------
#define NIN   64     // 2*B_IN
#define NOUT  32     // 2*B_OUT
#define NL    16     // B_OUT
#define NFIN  16     // F_IN
#define NFOUT 32     // F_OUT
#define NB    8      // BATCH
#define NGRID 24
#define NFREQ 31     // freqs -15..15
#define TOTL  5456   // sum_{l<16} (2l+1)^2
#define NTAB  540144 // 99*TOTL

// workspace float offsets
#define WF_F   0
#define WI_F   349184
#define DGC_F  523776
#define W64_F  785664
#define W32_F  789632
#define XFS_F  791616
#define FX_F   16536640
#define FYC_F  17933376
#define FZ_F   23520320
// total floats: 26,313,792  (~105.3 MB)

#define FZ_ELEMS 1396736   // 256*TOTL float2 elements per FZ buffer
#define NJOBS 1680
#define CNT_OFF (XFS_F + 3 * 2 * FZ_ELEMS)   // int slot after the 3 partial buffers (in XFS region)

__device__ __forceinline__ int offl(int l) { return l * (2 * l - 1) * (2 * l + 1) / 3; }

__device__ __forceinline__ double ipow(double x, int n) {
    double r = 1.0, p = x;
    while (n) { if (n & 1) r *= p; p *= p; n >>= 1; }
    return r;
}

// job table for k_fz: jobs ordered l=15 down to 0; per l: ceil(M/64)*ceil(N/64)*4 chunks
__device__ const int JOB_START[17] = {0, 256, 496, 720, 928, 1072, 1204, 1324, 1432,
                                      1496, 1552, 1600, 1640, 1656, 1668, 1676, 1680};

// ---------------- K0: build Wigner + twiddle tables ----------------
__global__ __launch_bounds__(256) void k_tables(float* __restrict__ WF, float* __restrict__ WI,
                                                float2* __restrict__ DGC, float2* __restrict__ W64,
                                                float2* __restrict__ W32) {
    __shared__ double lfs[32];   // log(n!)
    __shared__ double wdh[64];   // DH quadrature weights
    const double PI = 3.14159265358979323846264338327950288;
    int tid = threadIdx.x;
    if (tid < 32) {
        double f = 1.0;
        for (int i = 2; i <= tid; ++i) f *= (double)i;
        lfs[tid] = log(f);
    } else if (tid < 96) {
        int j = tid - 32;
        double x1 = PI * (double)(2 * j + 1) / 128.0;
        double ssum = 0.0;
        for (int k = 0; k < 32; ++k) ssum += sin(x1 * (double)(2 * k + 1)) / (double)(2 * k + 1);
        wdh[j] = (2.0 / 32.0) * sin(x1) * ssum;
    }
    __syncthreads();

    int t = blockIdx.x * 256 + tid;
    if (t >= NTAB) {
        int u = t - NTAB;
        if (u < 31 * 64) {              // forward twiddles e^{-2pi i (f-15) p/64}
            int f = u >> 6, p = u & 63;
            double ang = -2.0 * PI * (double)((f - 15) * p) / 64.0;
            W64[u] = make_float2((float)cos(ang), (float)sin(ang));
        } else {
            u -= 31 * 64;
            if (u < 31 * 32) {          // inverse twiddles e^{+2pi i (mu-15) p/32}
                int mu = u >> 5, p = u & 31;
                double ang = 2.0 * PI * (double)((mu - 15) * p) / 32.0;
                W32[u] = make_float2((float)cos(ang), (float)sin(ang));
            }
        }
        return;
    }
    // decode (l, src, a, b)
    int l = 0;
    while (l < 15 && t >= 99 * offl(l + 1)) l++;
    int n1 = 2 * l + 1, n2 = n1 * n1;
    int r = t - 99 * offl(l);
    int src = r / n2;
    int e = r - src * n2;
    int a = e / n1;
    int b = e - a * n1;
    int mp = a - l, m = b - l;

    double beta;
    if (src < 64)      beta = ((double)src + 0.5) * PI / 64.0;
    else if (src < 96) beta = ((double)(src - 64) + 0.5) * PI / 32.0;
    else               beta = (double)(src - 96 + 1) * PI / 24.0;

    double cb = cos(0.5 * beta), sb = sin(0.5 * beta);
    int smin = (m - mp) > 0 ? (m - mp) : 0;
    int smax = (l + m) < (l - mp) ? (l + m) : (l - mp);
    double pref = 0.5 * (lfs[l + mp] + lfs[l - mp] + lfs[l + m] + lfs[l - m]);
    double logden = lfs[l + m - smin] + lfs[smin] + lfs[mp - m + smin] + lfs[l - mp - smin];
    int p1 = 2 * l + m - mp - 2 * smin;
    int p2 = mp - m + 2 * smin;
    double term = exp(pref - logden) * ipow(cb, p1) * ipow(sb, p2);
    if ((mp - m + smin) & 1) term = -term;
    double acc = term;
    double rr = (sb * sb) / (cb * cb);
    for (int s = smin; s < smax; ++s) {
        term *= -rr * (double)((l + m - s) * (l - mp - s)) / (double)((s + 1) * (mp - m + s + 1));
        acc += term;
    }

    if (src < 64) {
        int j = src;
        WF[64 * offl(l) + (j * n1 + a) * n1 + b] = (float)(acc * wdh[j] / 8192.0);
    } else if (src < 96) {
        int j = src - 64;
        WI[32 * offl(l) + (j * n1 + a) * n1 + b] = (float)((double)(2 * l + 1) * acc);
    } else {
        int bi = src - 96;
        const double SCALING = 0.14433756729740644112728719512549; // 1/sqrt(48)
        double sc = acc * SCALING;
        int base = 24 * offl(l) + a * n1 + b;
        for (int ai = 0; ai < 8; ++ai) {
            double ang = (double)ai * (PI / 4.0) * (double)(a - l);  // conj phase: +i alpha m
            DGC[base + (bi * 8 + ai) * n2] = make_float2((float)(sc * cos(ang)), (float)(sc * sin(ang)));
        }
    }
}

// ---------------- K1: partial forward DFT2 (freqs -15..15), conj-pair symmetric ----------------
__global__ __launch_bounds__(256) void k_dft2(const float* __restrict__ x, const float2* __restrict__ W64,
                                              float2* __restrict__ XFS) {
    __shared__ float  xs[64 * 65];      // row stride 65 (bank decorrelation); E/O in place after butterfly
    __shared__ float2 a1[64 * 16];      // [p][n]; EA/OA in place after p-butterfly
    __shared__ float2 w64s[31 * 65];    // padded rows
    int tid = threadIdx.x;
    int slice = blockIdx.x;
    const float* xp = x + (size_t)slice * 4096;
    // load x: float4 global, scalar scatter into stride-65 rows
    for (int i = tid; i < 1024; i += 256) {
        float4 v = ((const float4*)xp)[i];
        int p = i >> 4, q0 = (i & 15) * 4;
        float* dst = xs + p * 65 + q0;
        dst[0] = v.x; dst[1] = v.y; dst[2] = v.z; dst[3] = v.w;
    }
    for (int i = tid; i < 31 * 64; i += 256) { int f = i >> 6, p = i & 63; w64s[f * 65 + p] = W64[i]; }
    __syncthreads();
    // in-place butterfly over q: x[q],x[64-q] -> E=x+x' (at q), O=x-x' (at 64-q), q=1..31
    for (int t = tid; t < 64 * 31; t += 256) {
        int p = t / 31, q = t - p * 31 + 1;
        float a = xs[p * 65 + q], b = xs[p * 65 + 64 - q];
        xs[p * 65 + q] = a + b;
        xs[p * 65 + 64 - q] = a - b;
    }
    __syncthreads();
    // phase 1: A[p][n] = x0 + (-1)^n x32 + sum_q E c - i sum_q O s   (w.y = -s)
    {
        int n = tid & 15;
        int prow = tid >> 4;
        float2 wreg[31];
#pragma unroll
        for (int q = 1; q <= 31; ++q) wreg[q - 1] = w64s[(n + 15) * 65 + q];
        float sg = (n & 1) ? -1.f : 1.f;
        for (int t2 = 0; t2 < 4; ++t2) {
            int p = prow + 16 * t2;
            const float* row = xs + p * 65;
            float re = row[0] + sg * row[32];
            float im = 0.f;
#pragma unroll
            for (int q = 1; q <= 31; ++q) {
                re += row[q] * wreg[q - 1].x;        // E*cos
                im += row[64 - q] * wreg[q - 1].y;   // O*(-sin)
            }
            a1[p * 16 + n] = make_float2(re, im);
        }
    }
    __syncthreads();
    // in-place butterfly over p on a1: rows p<->64-p -> EA (at p), OA (at 64-p), p=1..31
    for (int t = tid; t < 31 * 16; t += 256) {
        int p = (t >> 4) + 1, n = t & 15;
        float2 a = a1[p * 16 + n], b = a1[(64 - p) * 16 + n];
        a1[p * 16 + n] = make_float2(a.x + b.x, a.y + b.y);
        a1[(64 - p) * 16 + n] = make_float2(a.x - b.x, a.y - b.y);
    }
    __syncthreads();
    // phase 2: XF[mu][n] = A0 + (-1)^f A32 + sum_p [EA c + (OAi s, -OAr s)]  (c=w.x, s=-w.y)
    float2* outp = XFS + (size_t)slice * 961;
    {
        int n = tid & 15;
        int mrow = tid >> 4;
        for (int t2 = 0; t2 < 2; ++t2) {
            int mu = mrow + 16 * t2;
            if (mu >= 31) continue;
            int f = mu - 15;
            float sg = (f & 1) ? -1.f : 1.f;
            float2 A0 = a1[n], A32 = a1[32 * 16 + n];
            float re = A0.x + sg * A32.x;
            float im = A0.y + sg * A32.y;
            const float2* wrow = &w64s[mu * 65];
#pragma unroll
            for (int p = 1; p <= 31; ++p) {
                float2 EA = a1[p * 16 + n];
                float2 OA = a1[(64 - p) * 16 + n];
                float c = wrow[p].x;
                float s = -wrow[p].y;
                re += EA.x * c + OA.y * s;
                im += EA.y * c - OA.x * s;
            }
            outp[mu * 31 + (15 + n)] = make_float2(re, im);
            outp[(30 - mu) * 31 + (15 - n)] = make_float2(re, -im);
        }
    }
}

// ---------------- K2: Fy~ = conj(D)*ker, layout [(o,n)][(i,k)] per l ----------------
__global__ __launch_bounds__(256) void k_fy(const float* __restrict__ ker, const float2* __restrict__ DGC,
                                            float2* __restrict__ FYC) {
    int t = blockIdx.x * 256 + threadIdx.x;
    if (t >= 512 * TOTL) return;
    int l = 0;
    while (l < 15 && t >= 512 * offl(l + 1)) l++;
    int n1 = 2 * l + 1, n2 = n1 * n1;
    int r = t - 512 * offl(l);
    int k = r % n1; r /= n1;
    int i = r & 15; r >>= 4;
    int n = r % n1; int o = r / n1;
    const float2* dg = DGC + 24 * offl(l) + n * n1 + k;
    const float* kp = ker + (i * 32 + o) * 24;
    float re = 0.f, im = 0.f;
#pragma unroll
    for (int g = 0; g < 24; ++g) {
        float2 d = dg[g * n2];
        float kv = kp[g];
        re += d.x * kv; im += d.y * kv;
    }
    FYC[t] = make_float2(re, im);
}

// ---------------- K3: Fx = sum_j WF[l][j]*XF, layout [(b,m)][(i,k)] per l ----------------
__global__ __launch_bounds__(256) void k_fx(const float2* __restrict__ XFS, const float* __restrict__ WF,
                                            float2* __restrict__ FX) {
    int t = blockIdx.x * 256 + threadIdx.x;
    if (t >= 128 * TOTL) return;
    int l = 0;
    while (l < 15 && t >= 128 * offl(l + 1)) l++;
    int n1 = 2 * l + 1, n2 = n1 * n1;
    int r = t - 128 * offl(l);
    int k = r % n1; r /= n1;
    int i = r & 15; r >>= 4;
    int m = r % n1; int b = r / n1;
    const float* wf = WF + 64 * offl(l) + m * n1 + k;
    const float2* xf = XFS + (size_t)((b * 16 + i) * 64) * 961 + (m - l + 15) * 31 + (k - l + 15);
    float re = 0.f, im = 0.f;
#pragma unroll 8
    for (int j = 0; j < 64; ++j) {
        float w = wf[j * n2];
        float2 v = xf[j * 961];
        re += w * v.x; im += w * v.y;
    }
    FX[t] = make_float2(re, im);
}

// ---------------- K4: Fz complex GEMM, persistent blocks + dynamic jobs ----------------
__global__ __launch_bounds__(256) void k_fz(const float2* __restrict__ FX, const float2* __restrict__ FYC,
                                            float2* __restrict__ P0, float2* __restrict__ P1,
                                            float2* __restrict__ P2, float2* __restrict__ P3,
                                            int* __restrict__ cnt) {
    __shared__ float2 As[2][64][17];
    __shared__ float2 Bs[2][64][17];
    __shared__ int sjob;
    int tid = threadIdx.x;
    int kk0 = tid & 15;
    int rr0 = tid >> 4;
    int ty = tid >> 4;
    int tx = tid & 15;

    for (;;) {
        if (tid == 0) sjob = atomicAdd(cnt, 1);
        __syncthreads();
        int bid = sjob;
        if (bid >= NJOBS) return;

        int li = 0;
        while (li < 15 && bid >= JOB_START[li + 1]) ++li;
        int l = 15 - li;
        int n1 = 2 * l + 1;
        int ntn = (n1 + 1) >> 1;
        int r = bid - JOB_START[li];
        int ic = r & 3; r >>= 2;
        int tn = r % ntn;
        int tm = r / ntn;
        int M = 8 * n1, N = 32 * n1, K = 16 * n1;
        int kend = 4 * n1;
        int cbase = ic * kend;
        const float2* A = FX + 128 * offl(l);
        const float2* B = FYC + 512 * offl(l);
        float2* C = (ic == 0 ? P0 : ic == 1 ? P1 : ic == 2 ? P2 : P3) + 256 * offl(l);

        float acr[4][4] = {{0}}, aci[4][4] = {{0}};
        float2 ar[4], br[4];
        {
            int kc = kk0;
            bool kok = kc < kend;
#pragma unroll
            for (int s = 0; s < 4; ++s) {
                int row = rr0 + 16 * s;
                int grow = tm * 64 + row;
                ar[s] = (kok && grow < M) ? A[(size_t)grow * K + cbase + kc] : make_float2(0.f, 0.f);
                int gcol = tn * 64 + row;
                br[s] = (kok && gcol < N) ? B[(size_t)gcol * K + cbase + kc] : make_float2(0.f, 0.f);
            }
        }
        int cur = 0;
        for (int k0 = 0; k0 < kend; k0 += 16) {
#pragma unroll
            for (int s = 0; s < 4; ++s) {
                As[cur][rr0 + 16 * s][kk0] = ar[s];
                Bs[cur][rr0 + 16 * s][kk0] = br[s];
            }
            __syncthreads();
            if (k0 + 16 < kend) {
                int kc = k0 + 16 + kk0;
                bool kok = kc < kend;
#pragma unroll
                for (int s = 0; s < 4; ++s) {
                    int row = rr0 + 16 * s;
                    int grow = tm * 64 + row;
                    ar[s] = (kok && grow < M) ? A[(size_t)grow * K + cbase + kc] : make_float2(0.f, 0.f);
                    int gcol = tn * 64 + row;
                    br[s] = (kok && gcol < N) ? B[(size_t)gcol * K + cbase + kc] : make_float2(0.f, 0.f);
                }
            }
#pragma unroll
            for (int kk = 0; kk < 16; ++kk) {
                float2 av[4], bv[4];
#pragma unroll
                for (int ii = 0; ii < 4; ++ii) av[ii] = As[cur][ty + 16 * ii][kk];
#pragma unroll
                for (int jj = 0; jj < 4; ++jj) bv[jj] = Bs[cur][tx + 16 * jj][kk];
#pragma unroll
                for (int ii = 0; ii < 4; ++ii)
#pragma unroll
                    for (int jj = 0; jj < 4; ++jj) {
                        acr[ii][jj] += av[ii].x * bv[jj].x - av[ii].y * bv[jj].y;
                        aci[ii][jj] += av[ii].x * bv[jj].y + av[ii].y * bv[jj].x;
                    }
            }
            cur ^= 1;
        }
#pragma unroll
        for (int ii = 0; ii < 4; ++ii) {
            int row = tm * 64 + ty + 16 * ii;
            if (row >= M) continue;
#pragma unroll
            for (int jj = 0; jj < 4; ++jj) {
                int col = tn * 64 + tx + 16 * jj;
                if (col < N) C[(size_t)row * N + col] = make_float2(acr[ii][jj], aci[ii][jj]);
            }
        }
        __syncthreads();
    }
}

// ---------------- K4b: FZ = P0 + P1 + P2 + P3 ----------------
__global__ __launch_bounds__(256) void k_reduce(float4* __restrict__ FZ, const float4* __restrict__ P1,
                                                const float4* __restrict__ P2, const float4* __restrict__ P3) {
    int t = blockIdx.x * 256 + threadIdx.x;
    if (t >= FZ_ELEMS / 2) return;
    float4 a = FZ[t], b = P1[t], c = P2[t], d = P3[t];
    a.x += b.x + c.x + d.x;
    a.y += b.y + c.y + d.y;
    a.z += b.z + c.z + d.z;
    a.w += b.w + c.w + d.w;
    FZ[t] = a;
}

// ---------------- K5: fused S-assembly + inverse DFT2 + bias, conj-pair symmetric ----------------
__global__ __launch_bounds__(256) void k_out(const float2* __restrict__ FZ, const float* __restrict__ WI,
                                             const float2* __restrict__ W32, const float* __restrict__ bias,
                                             float* __restrict__ out) {
    __shared__ float2 s31[961];
    __shared__ float2 w32s[31 * 33];
    __shared__ float4 eoB[31 * 15];   // (Er,Ei,Or,Oi) per (mu, v=1..15)
    __shared__ float2 Tb[31 * 32];    // T[mu][q]
    __shared__ float2 Tc[15 * 32];    // (ETr, OTi) per (v=1..15, q)
    __shared__ float  T0r[32];
    __shared__ int    wbase[16], zbase[16], n1v[16], n32v[16];
    int tid = threadIdx.x;
    int slice = blockIdx.x;
    int j = slice & 31;
    int o = (slice >> 5) & 31;
    int b = slice >> 10;
    if (tid < 16) {
        int l = tid, n1 = 2 * l + 1;
        int off = offl(l);
        wbase[l] = 32 * off + j * n1 * n1;
        zbase[l] = 256 * off + b * 32 * n1 * n1 + o * n1;
        n1v[l] = n1; n32v[l] = 32 * n1;
    }
    for (int i = tid; i < 992; i += 256) { int mu = i >> 5, p = i & 31; w32s[mu * 33 + p] = W32[i]; }
    __syncthreads();
    // phase A: s31[mu,nu] = sum_l WI[l][j,m,n] * Fz[l][b,o,m,n]
    for (int t = tid; t < 961; t += 256) {
        int mu = t / 31;
        int nu = t - mu * 31;
        int m = mu - 15, n = nu - 15;
        int am = m < 0 ? -m : m, an = n < 0 ? -n : n;
        int l0 = am > an ? am : an;
        float re = 0.f, im = 0.f;
        for (int l = l0; l < 16; ++l) {
            int mi = m + l, ni = n + l;
            float w = WI[wbase[l] + mi * n1v[l] + ni];
            float2 z = FZ[zbase[l] + mi * n32v[l] + ni];
            re += w * z.x; im += w * z.y;
        }
        s31[t] = make_float2(re, im);
    }
    __syncthreads();
    // EO prep over nu: eoB[mu][v-1] = (S(v)+S(-v), S(v)-S(-v)) components
    for (int t = tid; t < 465; t += 256) {
        int mu = t / 15, v = t - mu * 15 + 1;
        float2 a = s31[mu * 31 + 15 + v];
        float2 c = s31[mu * 31 + 15 - v];
        eoB[t] = make_float4(a.x + c.x, a.y + c.y, a.x - c.x, a.y - c.y);
    }
    __syncthreads();
    // phase B: T[mu][q] = S[mu][0] + sum_v (E c + iO s);  c=cos(2pi v q/32), s=sin
    {
        int q = tid & 31, mg = tid >> 5;
        float2 wreg[15];
#pragma unroll
        for (int v = 1; v <= 15; ++v) wreg[v - 1] = w32s[(v + 15) * 33 + q];
        for (int t2 = 0; t2 < 4; ++t2) {
            int mu = mg + 8 * t2;
            if (mu < 31) {
                float2 c0 = s31[mu * 31 + 15];
                float tr = c0.x, ti = c0.y;
                const float4* ep = &eoB[mu * 15];
#pragma unroll
                for (int v = 0; v < 15; ++v) {
                    float4 e = ep[v];
                    float c = wreg[v].x, s = wreg[v].y;
                    tr += e.x * c - e.w * s;   // Er*c - Oi*s
                    ti += e.y * c + e.z * s;   // Ei*c + Or*s
                }
                Tb[mu * 32 + q] = make_float2(tr, ti);
            }
        }
    }
    __syncthreads();
    // Tc prep over mu: Tc[v-1][q] = (Tr(v)+Tr(-v), Ti(v)-Ti(-v)); T0r[q]
    for (int t = tid; t < 512; t += 256) {
        int v = t >> 5, q = t & 31;
        if (v == 0) T0r[q] = Tb[15 * 32 + q].x;
        else {
            float2 a = Tb[(15 + v) * 32 + q];
            float2 c = Tb[(15 - v) * 32 + q];
            Tc[(v - 1) * 32 + q] = make_float2(a.x + c.x, a.y - c.y);
        }
    }
    __syncthreads();
    // phase C: out[p][q] = T0r + sum_v (ETr cos - OTi sin) + bias
    float bv = bias[o];
    float* op = out + (size_t)slice * 1024;
    {
        int q = tid & 31, pg = tid >> 5;
        for (int t2 = 0; t2 < 4; ++t2) {
            int p = pg + 8 * t2;
            float acc = T0r[q];
#pragma unroll
            for (int v = 1; v <= 15; ++v) {
                float2 tc = Tc[(v - 1) * 32 + q];
                float2 w = w32s[(v + 15) * 33 + p];
                acc += tc.x * w.x - tc.y * w.y;
            }
            op[p * 32 + q] = acc + bv;
        }
    }
}

// ---------------- launch ----------------
extern "C" void kernel_launch(void* const* d_in, const int* in_sizes, int n_in,
                              void* d_out, int out_size, void* d_ws, size_t ws_size,
                              hipStream_t stream) {
    const float* x    = (const float*)d_in[0];
    const float* ker  = (const float*)d_in[1];
    const float* bias = (const float*)d_in[2];
    float* out = (float*)d_out;
    float* wsf = (float*)d_ws;

    float*  WF   = wsf + WF_F;
    float*  WI   = wsf + WI_F;
    float2* DGC  = (float2*)(wsf + DGC_F);
    float2* W64  = (float2*)(wsf + W64_F);
    float2* W32  = (float2*)(wsf + W32_F);
    float2* XFS  = (float2*)(wsf + XFS_F);
    float2* FX   = (float2*)(wsf + FX_F);
    float2* FYC  = (float2*)(wsf + FYC_F);
    float2* FZ   = (float2*)(wsf + FZ_F);
    float2* FZP1 = XFS;
    float2* FZP2 = FZP1 + FZ_ELEMS;
    float2* FZP3 = FZP2 + FZ_ELEMS;
    int*    CNT  = (int*)(wsf + CNT_OFF);

    hipLaunchKernelGGL(k_tables, dim3(2122),  dim3(256), 0, stream, WF, WI, DGC, W64, W32);
    hipLaunchKernelGGL(k_dft2,   dim3(8192),  dim3(256), 0, stream, x, W64, XFS);
    hipLaunchKernelGGL(k_fy,     dim3(10912), dim3(256), 0, stream, ker, DGC, FYC);
    hipLaunchKernelGGL(k_fx,     dim3(2728),  dim3(256), 0, stream, XFS, WF, FX);
    hipMemsetAsync(CNT, 0, sizeof(int), stream);
    hipLaunchKernelGGL(k_fz,     dim3(1024),  dim3(256), 0, stream, FX, FYC, FZ, FZP1, FZP2, FZP3, CNT);
    hipLaunchKernelGGL(k_reduce, dim3(2728),  dim3(256), 0, stream, (float4*)FZ, (const float4*)FZP1,
                                                                   (const float4*)FZP2, (const float4*)FZP3);
    hipLaunchKernelGGL(k_out,    dim3(8192),  dim3(256), 0, stream, FZ, WI, W32, bias, out);
}